// Round 3
// baseline (397.933 us; speedup 1.0000x reference)
//
#include <hip/hip_runtime.h>
#include <hip/hip_bf16.h>

#define MSEQ 2048

typedef __attribute__((ext_vector_type(8))) short short8;
typedef __attribute__((ext_vector_type(4))) short short4v;
typedef __attribute__((ext_vector_type(4))) float f32x4;

static __device__ __forceinline__ short bf16b(float f) {
    __hip_bfloat16 h = __float2bfloat16(f);   // RNE
    return *reinterpret_cast<short*>(&h);
}

// raw 2^x (input is pre-scaled by log2e at the K projection)
static __device__ __forceinline__ float fast_exp2(float x) {
    float r;
    asm("v_exp_f32 %0, %1" : "=v"(r) : "v"(x));
    return r;
}

// 16x16x16 bf16 MFMA (DQK=16 exact; score D-layout == PV A-frag layout)
static __device__ __forceinline__ f32x4 mfma16(short4v a, short4v b, f32x4 c) {
    return __builtin_amdgcn_mfma_f32_16x16x16bf16_1k(a, b, c, 0, 0, 0);
}

// async global->LDS, 16B per lane; LDS dest = wave-uniform base + lane*16
static __device__ __forceinline__ void gl_lds16(const void* g, void* l) {
    __builtin_amdgcn_global_load_lds(
        (const __attribute__((address_space(1))) unsigned int*)g,
        (__attribute__((address_space(3))) unsigned int*)l, 16, 0, 0);
}

// ---------------- x fp32 -> bf16 ----------------
__global__ __launch_bounds__(256) void xcvt_kernel(
    const float* __restrict__ x, unsigned short* __restrict__ xb)
{
    const size_t i = ((size_t)blockIdx.x * 256 + threadIdx.x) * 8;
    const float4 a = *(const float4*)(x + i);
    const float4 b = *(const float4*)(x + i + 4);
    short8 o;
    o[0]=bf16b(a.x); o[1]=bf16b(a.y); o[2]=bf16b(a.z); o[3]=bf16b(a.w);
    o[4]=bf16b(b.x); o[5]=bf16b(b.y); o[6]=bf16b(b.z); o[7]=bf16b(b.w);
    *(short8*)(xb + i) = o;
}

// ---------------- W -> WT[n][k] bf16 (n: 0..127 Wq | 128..255 Wk | 256..767 Wv) ----------------
__global__ __launch_bounds__(256) void wtrans_kernel(
    const float* __restrict__ Wq, const float* __restrict__ Wk,
    const float* __restrict__ Wv, unsigned short* __restrict__ WT)
{
    const int nt = blockIdx.x;   // 12 tiles of 64 n
    const int kt = blockIdx.y;   // 8 tiles of 64 k
    const int t  = threadIdx.x;
    const int k0 = kt*64;

    const float* W; int ld, n0;
    if (nt < 2)      { W = Wq; ld = 128; n0 = nt*64; }
    else if (nt < 4) { W = Wk; ld = 128; n0 = (nt-2)*64; }
    else             { W = Wv; ld = 512; n0 = (nt-4)*64; }

    __shared__ unsigned short Ts[64*72];   // [n][k], 144B rows

    #pragma unroll
    for (int s = 0; s < 4; ++s) {
        const int lin = s*256 + t;
        const int krow = lin >> 4, ng = lin & 15;
        const float4 v = *(const float4*)(W + (size_t)(k0+krow)*ld + n0 + ng*4);
        Ts[(ng*4+0)*72 + krow] = (unsigned short)bf16b(v.x);
        Ts[(ng*4+1)*72 + krow] = (unsigned short)bf16b(v.y);
        Ts[(ng*4+2)*72 + krow] = (unsigned short)bf16b(v.z);
        Ts[(ng*4+3)*72 + krow] = (unsigned short)bf16b(v.w);
    }
    __syncthreads();
    #pragma unroll
    for (int s = 0; s < 2; ++s) {
        const int lin = s*256 + t;
        const int nrow = lin >> 3, kg = lin & 7;
        *(short8*)(WT + (size_t)(nt*64 + nrow)*512 + k0 + kg*8) = *(const short8*)&Ts[nrow*72 + kg*8];
    }
}

// ---------------- Fused projection GEMM, bf16 MFMA, 64x128 tiles ----------------
// 768 blocks = exactly 3/CU (old 384 = 1.5/CU left half the machine idle in the tail).
// nt==1 (K) output pre-scaled by 0.25*log2(e) so attn uses raw v_exp_f32.
__global__ __launch_bounds__(256, 3) void proj_mfma(
    const unsigned short* __restrict__ xb, const unsigned short* __restrict__ WT,
    const float* __restrict__ bq, const float* __restrict__ bk, const float* __restrict__ bv,
    unsigned short* __restrict__ Qb, unsigned short* __restrict__ Kb, unsigned short* __restrict__ Vt)
{
    const int nt = blockIdx.x;        // 0..5 (0=Q,1=K,2..5=V)
    const int r0 = blockIdx.y * 64;   // m (128 tiles)
    const int n0 = nt * 128;
    const int t = threadIdx.x, w = t >> 6, lane = t & 63, l15 = lane & 15, quad = lane >> 4;
    const int qh = w >> 1, chh = w & 1;

    __shared__ short smem[128*72];    // staging 6144 shorts aliased; Ts V-mode needs 9216
    short* As = smem;                 // [64 m][32 k]
    short* Bs = smem + 64*32;         // [128 n][32 k]

    f32x4 acc[2][4];
    #pragma unroll
    for (int i = 0; i < 2; ++i)
        #pragma unroll
        for (int j = 0; j < 4; ++j) acc[i][j] = {0.f,0.f,0.f,0.f};

    const int arow = lane >> 2, akg = lane & 3;

    for (int kk = 0; kk < 512; kk += 32) {
        // 12 x 1KB chunks (4 A-rows16, 8 B-rows16): 3 per wave
        gl_lds16(xb + (size_t)(r0 + w*16 + arow)*512 + kk + akg*8, As + (w*16)*32);
        gl_lds16(WT + (size_t)(n0 + w*16 + arow)*512 + kk + akg*8, Bs + (w*16)*32);
        gl_lds16(WT + (size_t)(n0 + 64 + w*16 + arow)*512 + kk + akg*8, Bs + (64 + w*16)*32);
        __syncthreads();
        short8 Af[2], Bf[4];
        #pragma unroll
        for (int i = 0; i < 2; ++i) Af[i] = *(const short8*)&As[(qh*32 + i*16 + l15)*32 + quad*8];
        #pragma unroll
        for (int j = 0; j < 4; ++j) Bf[j] = *(const short8*)&Bs[(chh*64 + j*16 + l15)*32 + quad*8];
        #pragma unroll
        for (int i = 0; i < 2; ++i)
            #pragma unroll
            for (int j = 0; j < 4; ++j)
                acc[i][j] = __builtin_amdgcn_mfma_f32_16x16x32_bf16(Af[i], Bf[j], acc[i][j], 0, 0, 0);
        __syncthreads();
    }

    const float* bias = (nt == 0) ? bq : (nt == 1) ? bk : (bv + (nt-2)*128);
    const float kscale = (nt == 1) ? 0.36067376022224085f : 1.0f;  // 0.25 * log2(e)
    float bj[4];
    #pragma unroll
    for (int j = 0; j < 4; ++j) bj[j] = bias[chh*64 + j*16 + l15];

    short* Ts = smem;
    if (nt < 2) {       // row-major [64 m][136]
        #pragma unroll
        for (int i = 0; i < 2; ++i)
            #pragma unroll
            for (int j = 0; j < 4; ++j)
                #pragma unroll
                for (int r = 0; r < 4; ++r)
                    Ts[(qh*32 + i*16 + quad*4 + r)*136 + chh*64 + j*16 + l15] =
                        bf16b((acc[i][j][r] + bj[j]) * kscale);
    } else {            // transposed [128 ch][72 key]
        #pragma unroll
        for (int i = 0; i < 2; ++i)
            #pragma unroll
            for (int j = 0; j < 4; ++j)
                #pragma unroll
                for (int r = 0; r < 4; ++r)
                    Ts[(chh*64 + j*16 + l15)*72 + qh*32 + i*16 + quad*4 + r] =
                        bf16b(acc[i][j][r] + bj[j]);
    }
    __syncthreads();

    if (nt < 2) {
        unsigned short* Out = (nt == 0) ? Qb : Kb;
        #pragma unroll
        for (int s = 0; s < 4; ++s) {
            const int lin = s*256 + t, row = lin >> 4, seg = lin & 15;
            *(short8*)(Out + (size_t)(r0+row)*128 + seg*8) = *(const short8*)&Ts[row*136 + seg*8];
        }
    } else {
        const int b = r0 >> 11, key0 = r0 & 2047, chBase = (nt-2)*128;
        #pragma unroll
        for (int s = 0; s < 4; ++s) {
            const int lin = s*256 + t, row = lin >> 3, seg = lin & 7;
            *(short8*)(Vt + ((size_t)(b*512 + chBase + row))*MSEQ + key0 + seg*8) =
                *(const short8*)&Ts[row*72 + seg*8];
        }
    }
}

// ---------------- Fused masked attention: wave-autonomous, zero LDS, zero barriers ----------------
// Each wave: 16 q rows x ALL 2048 keys. Swapped QK (A=K,B=Q) at 16x16x16 puts
// P in exactly the PV A-frag layout -> P never leaves registers. No cross-wave
// reduction (wsum = 2 intra-wave shuffles). Two named prefetch stages give every
// K/V/mask fragment ~1.5 iterations (~200+ cyc) of load->use distance.
// Co-resident blocks share (b,h) (grid.x = bh; ids +-256 share x) -> K/V hit L1/L2.
#define LD_K(S)    (*(const short4v*)(Kp + ((size_t)(S) << 11)))
#define LD_M(S)    (*(const int4*)(mp + ((S) << 4)))
#define LD_V(S,V)  (*(const short4v*)(Vp + ((size_t)(V)*16*MSEQ) + ((S) << 4)))

#define ATT_STEP(KF, MK, V0, V1, V2, V3, SN)                                    \
  {                                                                             \
    f32x4 sc = {0.f,0.f,0.f,0.f};                                               \
    sc = mfma16(KF, qf, sc);                                                    \
    const float w0 = MK.x ? fast_exp2(fmaxf(sc[0], 0.f)) : 0.f;                 \
    const float w1 = MK.y ? fast_exp2(fmaxf(sc[1], 0.f)) : 0.f;                 \
    const float w2 = MK.z ? fast_exp2(fmaxf(sc[2], 0.f)) : 0.f;                 \
    const float w3 = MK.w ? fast_exp2(fmaxf(sc[3], 0.f)) : 0.f;                 \
    ws += (w0 + w1) + (w2 + w3);                                                \
    short4v pf; pf[0]=bf16b(w0); pf[1]=bf16b(w1); pf[2]=bf16b(w2); pf[3]=bf16b(w3); \
    O0 = mfma16(pf, V0, O0); O1 = mfma16(pf, V1, O1);                           \
    O2 = mfma16(pf, V2, O2); O3 = mfma16(pf, V3, O3);                           \
    KF = LD_K(SN); MK = LD_M(SN);                                               \
    V0 = LD_V(SN,0); V1 = LD_V(SN,1); V2 = LD_V(SN,2); V3 = LD_V(SN,3);         \
  }

__global__ __launch_bounds__(256, 4) void attn_mfma(
    const unsigned short* __restrict__ Qb, const unsigned short* __restrict__ Kb,
    const unsigned short* __restrict__ Vt, const int* __restrict__ mask,
    const float* __restrict__ gamma, float* __restrict__ out)
{
    const int bh = blockIdx.x;       // 32 (x-major so CU co-residents share bh)
    const int b  = bh >> 3, h = bh & 7;
    const int m0 = blockIdx.y * 64;  // 32 q-tiles of 64
    const int t  = threadIdx.x;
    const int w = t >> 6, lane = t & 63, l15 = lane & 15, quad = lane >> 4;
    const int mq = m0 + w*16;        // this wave's 16 q rows

    // Q B-frag: n=q=l15, k=d=quad*4+j
    const short4v qf = *(const short4v*)(Qb + (size_t)(b*MSEQ + mq + l15)*128 + h*16 + quad*4);

    const unsigned short* Kp = Kb + (size_t)(b*MSEQ + l15)*128 + h*16 + quad*4;
    const unsigned short* Vp = Vt + ((size_t)(b*512 + h*64 + l15))*MSEQ + quad*4;
    const int* mp = mask + b*MSEQ + quad*4;

    f32x4 O0 = {0.f,0.f,0.f,0.f}, O1 = {0.f,0.f,0.f,0.f};
    f32x4 O2 = {0.f,0.f,0.f,0.f}, O3 = {0.f,0.f,0.f,0.f};
    float ws = 0.f;

    short4v kfA = LD_K(0), kfB = LD_K(1);
    int4    mkA = LD_M(0), mkB = LD_M(1);
    short4v vA0 = LD_V(0,0), vA1 = LD_V(0,1), vA2 = LD_V(0,2), vA3 = LD_V(0,3);
    short4v vB0 = LD_V(1,0), vB1 = LD_V(1,1), vB2 = LD_V(1,2), vB3 = LD_V(1,3);

    for (int s = 0; s < 128; s += 2) {
        const int snA = (s + 2 < 128) ? s + 2 : s;       // tail reloads are harmless
        const int snB = (s + 3 < 128) ? s + 3 : s + 1;
        ATT_STEP(kfA, mkA, vA0, vA1, vA2, vA3, snA)
        ATT_STEP(kfB, mkB, vB0, vB1, vB2, vB3, snB)
    }

    // wsum for q=l15: fold the 4 quads
    ws += __shfl_xor(ws, 16, 64);
    ws += __shfl_xor(ws, 32, 64);
    const float g = gamma[0];
    // O lane layout: O[v][r] = O[q=quad*4+r][ch=v*16+l15]; fetch wsum[quad*4+r]
    float inv[4];
    #pragma unroll
    for (int r = 0; r < 4; ++r)
        inv[r] = g / fmaxf(__shfl(ws, quad*4 + r, 64), 1e-20f);

    float* op = out + (size_t)(b*MSEQ + mq + quad*4)*512 + h*64 + l15;
    #pragma unroll
    for (int r = 0; r < 4; ++r) {
        op[(size_t)r*512 +  0] = O0[r] * inv[r];
        op[(size_t)r*512 + 16] = O1[r] * inv[r];
        op[(size_t)r*512 + 32] = O2[r] * inv[r];
        op[(size_t)r*512 + 48] = O3[r] * inv[r];
    }
}

extern "C" void kernel_launch(void* const* d_in, const int* in_sizes, int n_in,
                              void* d_out, int out_size, void* d_ws, size_t ws_size,
                              hipStream_t stream) {
    const float* x     = (const float*)d_in[0];
    const int*   mask  = (const int*)  d_in[1];
    const float* Wq    = (const float*)d_in[2];
    const float* bq    = (const float*)d_in[3];
    const float* Wk    = (const float*)d_in[4];
    const float* bk    = (const float*)d_in[5];
    const float* Wv    = (const float*)d_in[6];
    const float* bv    = (const float*)d_in[7];
    const float* gamma = (const float*)d_in[8];
    float* outp = (float*)d_out;

    // ws (bf16 shorts): xb 8MB | WT 0.75MB | Qb 2MB | Kb 2MB | Vt 8MB
    unsigned short* xb = (unsigned short*)d_ws;
    unsigned short* WT = xb + (size_t)8192*512;
    unsigned short* Qb = WT + (size_t)768*512;
    unsigned short* Kb = Qb + (size_t)8192*128;
    unsigned short* Vt = Kb + (size_t)8192*128;

    xcvt_kernel<<<2048, 256, 0, stream>>>(x, xb);
    wtrans_kernel<<<dim3(12, 8), 256, 0, stream>>>(Wq, Wk, Wv, WT);
    proj_mfma<<<dim3(6, 128), 256, 0, stream>>>(xb, WT, bq, bk, bv, Qb, Kb, Vt);
    attn_mfma<<<dim3(32, 32), 256, 0, stream>>>(Qb, Kb, Vt, mask, gamma, outp);
}

// Round 4
// 156.568 us; speedup vs baseline: 2.5416x; 2.5416x over previous
//
#include <hip/hip_runtime.h>
#include <hip/hip_bf16.h>

#define MSEQ 2048

typedef __attribute__((ext_vector_type(8))) short short8;
typedef __attribute__((ext_vector_type(4))) short short4v;
typedef __attribute__((ext_vector_type(4))) float f32x4;

static __device__ __forceinline__ short bf16b(float f) {
    __hip_bfloat16 h = __float2bfloat16(f);   // RNE
    return *reinterpret_cast<short*>(&h);
}

// raw 2^x (input is pre-scaled by log2e at the K projection)
static __device__ __forceinline__ float fast_exp2(float x) {
    float r;
    asm("v_exp_f32 %0, %1" : "=v"(r) : "v"(x));
    return r;
}

// 16x16x16 bf16 MFMA (DQK=16 exact; score D-layout == PV A-frag layout)
static __device__ __forceinline__ f32x4 mfma16(short4v a, short4v b, f32x4 c) {
    return __builtin_amdgcn_mfma_f32_16x16x16bf16_1k(a, b, c, 0, 0, 0);
}

// async global->LDS, 16B per lane; LDS dest = wave-uniform base + lane*16
static __device__ __forceinline__ void gl_lds16(const void* g, void* l) {
    __builtin_amdgcn_global_load_lds(
        (const __attribute__((address_space(1))) unsigned int*)g,
        (__attribute__((address_space(3))) unsigned int*)l, 16, 0, 0);
}

// ---------------- x fp32 -> bf16 ----------------
__global__ __launch_bounds__(256) void xcvt_kernel(
    const float* __restrict__ x, unsigned short* __restrict__ xb)
{
    const size_t i = ((size_t)blockIdx.x * 256 + threadIdx.x) * 8;
    const float4 a = *(const float4*)(x + i);
    const float4 b = *(const float4*)(x + i + 4);
    short8 o;
    o[0]=bf16b(a.x); o[1]=bf16b(a.y); o[2]=bf16b(a.z); o[3]=bf16b(a.w);
    o[4]=bf16b(b.x); o[5]=bf16b(b.y); o[6]=bf16b(b.z); o[7]=bf16b(b.w);
    *(short8*)(xb + i) = o;
}

// ---------------- W -> WT[n][k] bf16 (n: 0..127 Wq | 128..255 Wk | 256..767 Wv) ----------------
__global__ __launch_bounds__(256) void wtrans_kernel(
    const float* __restrict__ Wq, const float* __restrict__ Wk,
    const float* __restrict__ Wv, unsigned short* __restrict__ WT)
{
    const int nt = blockIdx.x;   // 12 tiles of 64 n
    const int kt = blockIdx.y;   // 8 tiles of 64 k
    const int t  = threadIdx.x;
    const int k0 = kt*64;

    const float* W; int ld, n0;
    if (nt < 2)      { W = Wq; ld = 128; n0 = nt*64; }
    else if (nt < 4) { W = Wk; ld = 128; n0 = (nt-2)*64; }
    else             { W = Wv; ld = 512; n0 = (nt-4)*64; }

    __shared__ unsigned short Ts[64*72];   // [n][k], 144B rows

    #pragma unroll
    for (int s = 0; s < 4; ++s) {
        const int lin = s*256 + t;
        const int krow = lin >> 4, ng = lin & 15;
        const float4 v = *(const float4*)(W + (size_t)(k0+krow)*ld + n0 + ng*4);
        Ts[(ng*4+0)*72 + krow] = (unsigned short)bf16b(v.x);
        Ts[(ng*4+1)*72 + krow] = (unsigned short)bf16b(v.y);
        Ts[(ng*4+2)*72 + krow] = (unsigned short)bf16b(v.z);
        Ts[(ng*4+3)*72 + krow] = (unsigned short)bf16b(v.w);
    }
    __syncthreads();
    #pragma unroll
    for (int s = 0; s < 2; ++s) {
        const int lin = s*256 + t;
        const int nrow = lin >> 3, kg = lin & 7;
        *(short8*)(WT + (size_t)(nt*64 + nrow)*512 + k0 + kg*8) = *(const short8*)&Ts[nrow*72 + kg*8];
    }
}

// ---------------- Fused projection GEMM, bf16 MFMA, 64x128 tiles ----------------
// 768 blocks = exactly 3/CU. nt==1 (K) output pre-scaled by 0.25*log2(e).
__global__ __launch_bounds__(256, 3) void proj_mfma(
    const unsigned short* __restrict__ xb, const unsigned short* __restrict__ WT,
    const float* __restrict__ bq, const float* __restrict__ bk, const float* __restrict__ bv,
    unsigned short* __restrict__ Qb, unsigned short* __restrict__ Kb, unsigned short* __restrict__ Vt)
{
    const int nt = blockIdx.x;        // 0..5 (0=Q,1=K,2..5=V)
    const int r0 = blockIdx.y * 64;   // m (128 tiles)
    const int n0 = nt * 128;
    const int t = threadIdx.x, w = t >> 6, lane = t & 63, l15 = lane & 15, quad = lane >> 4;
    const int qh = w >> 1, chh = w & 1;

    __shared__ short smem[128*72];    // staging 6144 shorts aliased; Ts V-mode needs 9216
    short* As = smem;                 // [64 m][32 k]
    short* Bs = smem + 64*32;         // [128 n][32 k]

    f32x4 acc[2][4];
    #pragma unroll
    for (int i = 0; i < 2; ++i)
        #pragma unroll
        for (int j = 0; j < 4; ++j) acc[i][j] = {0.f,0.f,0.f,0.f};

    const int arow = lane >> 2, akg = lane & 3;

    for (int kk = 0; kk < 512; kk += 32) {
        gl_lds16(xb + (size_t)(r0 + w*16 + arow)*512 + kk + akg*8, As + (w*16)*32);
        gl_lds16(WT + (size_t)(n0 + w*16 + arow)*512 + kk + akg*8, Bs + (w*16)*32);
        gl_lds16(WT + (size_t)(n0 + 64 + w*16 + arow)*512 + kk + akg*8, Bs + (64 + w*16)*32);
        __syncthreads();
        short8 Af[2], Bf[4];
        #pragma unroll
        for (int i = 0; i < 2; ++i) Af[i] = *(const short8*)&As[(qh*32 + i*16 + l15)*32 + quad*8];
        #pragma unroll
        for (int j = 0; j < 4; ++j) Bf[j] = *(const short8*)&Bs[(chh*64 + j*16 + l15)*32 + quad*8];
        #pragma unroll
        for (int i = 0; i < 2; ++i)
            #pragma unroll
            for (int j = 0; j < 4; ++j)
                acc[i][j] = __builtin_amdgcn_mfma_f32_16x16x32_bf16(Af[i], Bf[j], acc[i][j], 0, 0, 0);
        __syncthreads();
    }

    const float* bias = (nt == 0) ? bq : (nt == 1) ? bk : (bv + (nt-2)*128);
    const float kscale = (nt == 1) ? 0.36067376022224085f : 1.0f;  // 0.25 * log2(e)
    float bj[4];
    #pragma unroll
    for (int j = 0; j < 4; ++j) bj[j] = bias[chh*64 + j*16 + l15];

    short* Ts = smem;
    if (nt < 2) {       // row-major [64 m][136]
        #pragma unroll
        for (int i = 0; i < 2; ++i)
            #pragma unroll
            for (int j = 0; j < 4; ++j)
                #pragma unroll
                for (int r = 0; r < 4; ++r)
                    Ts[(qh*32 + i*16 + quad*4 + r)*136 + chh*64 + j*16 + l15] =
                        bf16b((acc[i][j][r] + bj[j]) * kscale);
    } else {            // transposed [128 ch][72 key]
        #pragma unroll
        for (int i = 0; i < 2; ++i)
            #pragma unroll
            for (int j = 0; j < 4; ++j)
                #pragma unroll
                for (int r = 0; r < 4; ++r)
                    Ts[(chh*64 + j*16 + l15)*72 + qh*32 + i*16 + quad*4 + r] =
                        bf16b(acc[i][j][r] + bj[j]);
    }
    __syncthreads();

    if (nt < 2) {
        unsigned short* Out = (nt == 0) ? Qb : Kb;
        #pragma unroll
        for (int s = 0; s < 4; ++s) {
            const int lin = s*256 + t, row = lin >> 4, seg = lin & 15;
            *(short8*)(Out + (size_t)(r0+row)*128 + seg*8) = *(const short8*)&Ts[row*136 + seg*8];
        }
    } else {
        const int b = r0 >> 11, key0 = r0 & 2047, chBase = (nt-2)*128;
        #pragma unroll
        for (int s = 0; s < 4; ++s) {
            const int lin = s*256 + t, row = lin >> 3, seg = lin & 7;
            *(short8*)(Vt + ((size_t)(b*512 + chBase + row))*MSEQ + key0 + seg*8) =
                *(const short8*)&Ts[row*72 + seg*8];
        }
    }
}

// ---------------- Fused masked attention ----------------
// LDS-staged K/V/mask (async gl_lds16, double-buffered, one vmcnt(0)+barrier per
// 64-key tile = T3 minimum 2-phase) + register-resident P (swapped-QK mfma16:
// score D-layout IS the PV A-frag layout). 4 waves x 16 q-rows. V^T tile is
// XOR-swizzled (granule ^= ch&7) via pre-swizzled GLOBAL source (LDS dest stays
// linear, read applies the same involution) -> dense ds_reads, no 16-way conflict.
// Grid: x = q-tile, y = bh -> consecutive blocks share (b,h) K/V in L2.
__global__ __launch_bounds__(256, 4) void attn_mfma(
    const unsigned short* __restrict__ Qb, const unsigned short* __restrict__ Kb,
    const unsigned short* __restrict__ Vt, const int* __restrict__ mask,
    const float* __restrict__ gamma, float* __restrict__ out)
{
    const int mt = blockIdx.x;       // 32 q-tiles of 64
    const int bh = blockIdx.y;       // 32
    const int b  = bh >> 3, h = bh & 7;
    const int m0 = mt * 64;
    const int t  = threadIdx.x;
    const int w = t >> 6, lane = t & 63, l15 = lane & 15, quad = lane >> 4;
    const int mq = m0 + w*16;        // this wave's 16 q rows

    __shared__ __align__(16) short Ks[2][64*16];   // [key][16 d]  (32B rows, dense)
    __shared__ __align__(16) short Vs[2][64*64];   // [ch][64 key] swizzled granules
    __shared__ __align__(16) int   Ms[2][64];

    // Q B-frag: n=q=l15, k=d=quad*4+j  (one-time global load)
    const short4v qf = *(const short4v*)(Qb + (size_t)(b*MSEQ + mq + l15)*128 + h*16 + quad*4);

    // ---- staging source pointers (per-lane) ----
    // K: lane -> key=lane>>1, 16B half=(lane&1); two instrs cover 64 keys.
    const unsigned short* Kg = Kb + (size_t)(b*MSEQ + (lane>>1))*128 + h*16 + (lane&1)*8;
    // V: wave w stages granule-swizzled rows; instr j covers ch rows j*8+ (lane>>3).
    // source granule = (lane&7) ^ ((lane>>3)&7)  [involution; read applies same XOR]
    const int vj0 = 2*w;
    const unsigned short* Vg0 = Vt + (size_t)(b*512 + h*64 + vj0*8 + (lane>>3))*MSEQ
                                   + (((lane&7) ^ ((lane>>3)&7)) * 8);
    const unsigned short* Vg1 = Vg0 + (size_t)8*MSEQ;
    const int* Mg = mask + b*MSEQ + lane*4;   // lanes<16 only

#define ATT_STAGE(bufi, kn)                                                   \
  {                                                                           \
    gl_lds16(Vg0 + (kn), &Vs[bufi][vj0*512]);                                 \
    gl_lds16(Vg1 + (kn), &Vs[bufi][(vj0+1)*512]);                             \
    if (w == 0) {                                                             \
      gl_lds16(Kg + (size_t)(kn)*128,      &Ks[bufi][0]);                     \
      gl_lds16(Kg + (size_t)((kn)+32)*128, &Ks[bufi][32*16]);                 \
    }                                                                         \
    if (w == 1 && lane < 16) gl_lds16(Mg + (kn), &Ms[bufi][0]);               \
  }

    f32x4 O[4];
    #pragma unroll
    for (int v = 0; v < 4; ++v) O[v] = {0.f,0.f,0.f,0.f};
    float ws = 0.f;

    ATT_STAGE(0, 0)
    asm volatile("s_waitcnt vmcnt(0)" ::: "memory");
    __syncthreads();

    for (int kt = 0; kt < 32; ++kt) {
        const int cur = kt & 1;
        if (kt < 31) ATT_STAGE(cur ^ 1, (kt+1)*64)

        const short* Kc = Ks[cur];
        const short* Vc = Vs[cur];
        const int*   Mc = Ms[cur];

        #pragma unroll
        for (int s = 0; s < 4; ++s) {
            const short4v kf = *(const short4v*)&Kc[(s*16 + l15)*16 + quad*4];
            const int4 mk = *(const int4*)&Mc[s*16 + quad*4];
            f32x4 sc = {0.f,0.f,0.f,0.f};
            sc = mfma16(kf, qf, sc);
            // lane: q=l15, keys = s*16 + quad*4 + r; K pre-scaled by 0.25*log2e
            const float w0 = mk.x ? fast_exp2(fmaxf(sc[0], 0.f)) : 0.f;
            const float w1 = mk.y ? fast_exp2(fmaxf(sc[1], 0.f)) : 0.f;
            const float w2 = mk.z ? fast_exp2(fmaxf(sc[2], 0.f)) : 0.f;
            const float w3 = mk.w ? fast_exp2(fmaxf(sc[3], 0.f)) : 0.f;
            ws += (w0 + w1) + (w2 + w3);
            short4v pf;
            pf[0]=bf16b(w0); pf[1]=bf16b(w1); pf[2]=bf16b(w2); pf[3]=bf16b(w3);
            #pragma unroll
            for (int v = 0; v < 4; ++v) {
                const int ch = v*16 + l15;
                const int g = (2*s + (quad>>1)) ^ (ch & 7);    // swizzled granule
                const short4v vf = *(const short4v*)&Vc[ch*64 + g*8 + (quad&1)*4];
                O[v] = mfma16(pf, vf, O[v]);
            }
        }
        asm volatile("s_waitcnt vmcnt(0)" ::: "memory");
        __syncthreads();
    }

    // wsum for q=l15: fold the 4 quads (every lane ends with full sum)
    ws += __shfl_xor(ws, 16, 64);
    ws += __shfl_xor(ws, 32, 64);
    const float g = gamma[0];
    // O lane layout: O[v][r] = O[q=quad*4+r][ch=v*16+l15]
    float inv[4];
    #pragma unroll
    for (int r = 0; r < 4; ++r)
        inv[r] = g / fmaxf(__shfl(ws, quad*4 + r, 64), 1e-20f);

    float* op = out + (size_t)(b*MSEQ + mq + quad*4)*512 + h*64 + l15;
    #pragma unroll
    for (int r = 0; r < 4; ++r) {
        op[(size_t)r*512 +  0] = O[0][r] * inv[r];
        op[(size_t)r*512 + 16] = O[1][r] * inv[r];
        op[(size_t)r*512 + 32] = O[2][r] * inv[r];
        op[(size_t)r*512 + 48] = O[3][r] * inv[r];
    }
#undef ATT_STAGE
}

extern "C" void kernel_launch(void* const* d_in, const int* in_sizes, int n_in,
                              void* d_out, int out_size, void* d_ws, size_t ws_size,
                              hipStream_t stream) {
    const float* x     = (const float*)d_in[0];
    const int*   mask  = (const int*)  d_in[1];
    const float* Wq    = (const float*)d_in[2];
    const float* bq    = (const float*)d_in[3];
    const float* Wk    = (const float*)d_in[4];
    const float* bk    = (const float*)d_in[5];
    const float* Wv    = (const float*)d_in[6];
    const float* bv    = (const float*)d_in[7];
    const float* gamma = (const float*)d_in[8];
    float* outp = (float*)d_out;

    // ws (bf16 shorts): xb 8MB | WT 0.75MB | Qb 2MB | Kb 2MB | Vt 8MB
    unsigned short* xb = (unsigned short*)d_ws;
    unsigned short* WT = xb + (size_t)8192*512;
    unsigned short* Qb = WT + (size_t)768*512;
    unsigned short* Kb = Qb + (size_t)8192*128;
    unsigned short* Vt = Kb + (size_t)8192*128;

    xcvt_kernel<<<2048, 256, 0, stream>>>(x, xb);
    wtrans_kernel<<<dim3(12, 8), 256, 0, stream>>>(Wq, Wk, Wv, WT);
    proj_mfma<<<dim3(6, 128), 256, 0, stream>>>(xb, WT, bq, bk, bv, Qb, Kb, Vt);
    attn_mfma<<<dim3(32, 32), 256, 0, stream>>>(Qb, Kb, Vt, mask, gamma, outp);
}

// Round 5
// 156.397 us; speedup vs baseline: 2.5444x; 1.0011x over previous
//
#include <hip/hip_runtime.h>
#include <hip/hip_bf16.h>

#define MSEQ 2048

typedef __attribute__((ext_vector_type(8))) short short8;
typedef __attribute__((ext_vector_type(4))) short short4v;
typedef __attribute__((ext_vector_type(4))) float f32x4;

static __device__ __forceinline__ short bf16b(float f) {
    __hip_bfloat16 h = __float2bfloat16(f);   // RNE
    return *reinterpret_cast<short*>(&h);
}

// raw 2^x (input is pre-scaled by log2e at the K projection)
static __device__ __forceinline__ float fast_exp2(float x) {
    float r;
    asm("v_exp_f32 %0, %1" : "=v"(r) : "v"(x));
    return r;
}

// 16x16x16 bf16 MFMA (DQK=16 exact; score D-layout == PV A-frag layout)
static __device__ __forceinline__ f32x4 mfma16(short4v a, short4v b, f32x4 c) {
    return __builtin_amdgcn_mfma_f32_16x16x16bf16_1k(a, b, c, 0, 0, 0);
}

// async global->LDS, 16B per lane; LDS dest = wave-uniform base + lane*16
static __device__ __forceinline__ void gl_lds16(const void* g, void* l) {
    __builtin_amdgcn_global_load_lds(
        (const __attribute__((address_space(1))) unsigned int*)g,
        (__attribute__((address_space(3))) unsigned int*)l, 16, 0, 0);
}

// ---------------- x fp32 -> bf16 ----------------
__global__ __launch_bounds__(256) void xcvt_kernel(
    const float* __restrict__ x, unsigned short* __restrict__ xb)
{
    const size_t i = ((size_t)blockIdx.x * 256 + threadIdx.x) * 8;
    const float4 a = *(const float4*)(x + i);
    const float4 b = *(const float4*)(x + i + 4);
    short8 o;
    o[0]=bf16b(a.x); o[1]=bf16b(a.y); o[2]=bf16b(a.z); o[3]=bf16b(a.w);
    o[4]=bf16b(b.x); o[5]=bf16b(b.y); o[6]=bf16b(b.z); o[7]=bf16b(b.w);
    *(short8*)(xb + i) = o;
}

// ---------------- W -> WT[n][k] bf16 (n: 0..127 Wq | 128..255 Wk | 256..767 Wv) ----------------
__global__ __launch_bounds__(256) void wtrans_kernel(
    const float* __restrict__ Wq, const float* __restrict__ Wk,
    const float* __restrict__ Wv, unsigned short* __restrict__ WT)
{
    const int nt = blockIdx.x;   // 12 tiles of 64 n
    const int kt = blockIdx.y;   // 8 tiles of 64 k
    const int t  = threadIdx.x;
    const int k0 = kt*64;

    const float* W; int ld, n0;
    if (nt < 2)      { W = Wq; ld = 128; n0 = nt*64; }
    else if (nt < 4) { W = Wk; ld = 128; n0 = (nt-2)*64; }
    else             { W = Wv; ld = 512; n0 = (nt-4)*64; }

    __shared__ unsigned short Ts[64*72];   // [n][k], 144B rows

    #pragma unroll
    for (int s = 0; s < 4; ++s) {
        const int lin = s*256 + t;
        const int krow = lin >> 4, ng = lin & 15;
        const float4 v = *(const float4*)(W + (size_t)(k0+krow)*ld + n0 + ng*4);
        Ts[(ng*4+0)*72 + krow] = (unsigned short)bf16b(v.x);
        Ts[(ng*4+1)*72 + krow] = (unsigned short)bf16b(v.y);
        Ts[(ng*4+2)*72 + krow] = (unsigned short)bf16b(v.z);
        Ts[(ng*4+3)*72 + krow] = (unsigned short)bf16b(v.w);
    }
    __syncthreads();
    #pragma unroll
    for (int s = 0; s < 2; ++s) {
        const int lin = s*256 + t;
        const int nrow = lin >> 3, kg = lin & 7;
        *(short8*)(WT + (size_t)(nt*64 + nrow)*512 + k0 + kg*8) = *(const short8*)&Ts[nrow*72 + kg*8];
    }
}

// ---------------- Fused projection GEMM, bf16 MFMA, 64x128 tiles ----------------
// 768 blocks = exactly 3/CU. nt==1 (K) output pre-scaled by 0.25*log2(e).
__global__ __launch_bounds__(256, 3) void proj_mfma(
    const unsigned short* __restrict__ xb, const unsigned short* __restrict__ WT,
    const float* __restrict__ bq, const float* __restrict__ bk, const float* __restrict__ bv,
    unsigned short* __restrict__ Qb, unsigned short* __restrict__ Kb, unsigned short* __restrict__ Vt)
{
    const int nt = blockIdx.x;        // 0..5 (0=Q,1=K,2..5=V)
    const int r0 = blockIdx.y * 64;   // m (128 tiles)
    const int n0 = nt * 128;
    const int t = threadIdx.x, w = t >> 6, lane = t & 63, l15 = lane & 15, quad = lane >> 4;
    const int qh = w >> 1, chh = w & 1;

    __shared__ short smem[128*72];    // staging 6144 shorts aliased; Ts V-mode needs 9216
    short* As = smem;                 // [64 m][32 k]
    short* Bs = smem + 64*32;         // [128 n][32 k]

    f32x4 acc[2][4];
    #pragma unroll
    for (int i = 0; i < 2; ++i)
        #pragma unroll
        for (int j = 0; j < 4; ++j) acc[i][j] = {0.f,0.f,0.f,0.f};

    const int arow = lane >> 2, akg = lane & 3;

    for (int kk = 0; kk < 512; kk += 32) {
        gl_lds16(xb + (size_t)(r0 + w*16 + arow)*512 + kk + akg*8, As + (w*16)*32);
        gl_lds16(WT + (size_t)(n0 + w*16 + arow)*512 + kk + akg*8, Bs + (w*16)*32);
        gl_lds16(WT + (size_t)(n0 + 64 + w*16 + arow)*512 + kk + akg*8, Bs + (64 + w*16)*32);
        __syncthreads();
        short8 Af[2], Bf[4];
        #pragma unroll
        for (int i = 0; i < 2; ++i) Af[i] = *(const short8*)&As[(qh*32 + i*16 + l15)*32 + quad*8];
        #pragma unroll
        for (int j = 0; j < 4; ++j) Bf[j] = *(const short8*)&Bs[(chh*64 + j*16 + l15)*32 + quad*8];
        #pragma unroll
        for (int i = 0; i < 2; ++i)
            #pragma unroll
            for (int j = 0; j < 4; ++j)
                acc[i][j] = __builtin_amdgcn_mfma_f32_16x16x32_bf16(Af[i], Bf[j], acc[i][j], 0, 0, 0);
        __syncthreads();
    }

    const float* bias = (nt == 0) ? bq : (nt == 1) ? bk : (bv + (nt-2)*128);
    const float kscale = (nt == 1) ? 0.36067376022224085f : 1.0f;  // 0.25 * log2(e)
    float bj[4];
    #pragma unroll
    for (int j = 0; j < 4; ++j) bj[j] = bias[chh*64 + j*16 + l15];

    short* Ts = smem;
    if (nt < 2) {       // row-major [64 m][136]
        #pragma unroll
        for (int i = 0; i < 2; ++i)
            #pragma unroll
            for (int j = 0; j < 4; ++j)
                #pragma unroll
                for (int r = 0; r < 4; ++r)
                    Ts[(qh*32 + i*16 + quad*4 + r)*136 + chh*64 + j*16 + l15] =
                        bf16b((acc[i][j][r] + bj[j]) * kscale);
    } else {            // transposed [128 ch][72 key]
        #pragma unroll
        for (int i = 0; i < 2; ++i)
            #pragma unroll
            for (int j = 0; j < 4; ++j)
                #pragma unroll
                for (int r = 0; r < 4; ++r)
                    Ts[(chh*64 + j*16 + l15)*72 + qh*32 + i*16 + quad*4 + r] =
                        bf16b(acc[i][j][r] + bj[j]);
    }
    __syncthreads();

    if (nt < 2) {
        unsigned short* Out = (nt == 0) ? Qb : Kb;
        #pragma unroll
        for (int s = 0; s < 4; ++s) {
            const int lin = s*256 + t, row = lin >> 4, seg = lin & 15;
            *(short8*)(Out + (size_t)(r0+row)*128 + seg*8) = *(const short8*)&Ts[row*136 + seg*8];
        }
    } else {
        const int b = r0 >> 11, key0 = r0 & 2047, chBase = (nt-2)*128;
        #pragma unroll
        for (int s = 0; s < 4; ++s) {
            const int lin = s*256 + t, row = lin >> 3, seg = lin & 7;
            *(short8*)(Vt + ((size_t)(b*512 + chBase + row))*MSEQ + key0 + seg*8) =
                *(const short8*)&Ts[row*72 + seg*8];
        }
    }
}

// ---------------- Fused masked attention ----------------
// LDS-staged K/V/mask (async gl_lds16, double-buffered, 2-phase) + register-
// resident P (swapped-QK mfma16). New in this round:
//  (a) XCD-aware bijective block remap: each XCD owns 4 consecutive bh slices
//      (1.28MB K+V) -> L2-resident, FETCH back to ~13MB, staging latency ~200cy.
//  (b) K granule XOR-swizzle (g ^= (key>>2)&1, both-sides involution via
//      pre-swizzled global source): K ds_read 4-way conflict -> free 2-way.
// V keeps its granule swizzle (already 2-way per half-wave).
__global__ __launch_bounds__(256, 4) void attn_mfma(
    const unsigned short* __restrict__ Qb, const unsigned short* __restrict__ Kb,
    const unsigned short* __restrict__ Vt, const int* __restrict__ mask,
    const float* __restrict__ gamma, float* __restrict__ out)
{
    // XCD-aware remap: dispatch id bid -> XCD bid&7 (round-robin). Give XCD x
    // the logical blocks [x*128, x*128+128) = bh in [x*4, x*4+4), all 32 mt.
    const int bid = blockIdx.y * 32 + blockIdx.x;      // 1024 blocks, 1024%8==0
    const int lin = (bid & 7) * 128 + (bid >> 3);      // bijective
    const int mt = lin & 31;        // q-tile
    const int bh = lin >> 5;        // (b,h)
    const int b  = bh >> 3, h = bh & 7;
    const int m0 = mt * 64;
    const int t  = threadIdx.x;
    const int w = t >> 6, lane = t & 63, l15 = lane & 15, quad = lane >> 4;
    const int mq = m0 + w*16;        // this wave's 16 q rows

    __shared__ __align__(16) short Ks[2][64*16];   // [key][16 d], granule-swizzled
    __shared__ __align__(16) short Vs[2][64*64];   // [ch][64 key], granule-swizzled
    __shared__ __align__(16) int   Ms[2][64];

    // Q B-frag: n=q=l15, k=d=quad*4+j  (one-time global load)
    const short4v qf = *(const short4v*)(Qb + (size_t)(b*MSEQ + mq + l15)*128 + h*16 + quad*4);

    // ---- staging source pointers (per-lane) ----
    // K: lane -> key=lane>>1, granule=(lane&1)^((key>>2)&1) [(key>>2)=lane>>3].
    const unsigned short* Kg = Kb + (size_t)(b*MSEQ + (lane>>1))*128 + h*16
                                  + (((lane&1) ^ ((lane>>3)&1))*8);
    // V: wave w stages granule-swizzled rows; instr j covers ch rows j*8+(lane>>3).
    // source granule = (lane&7) ^ ((lane>>3)&7)  [involution; read applies same XOR]
    const int vj0 = 2*w;
    const unsigned short* Vg0 = Vt + (size_t)(b*512 + h*64 + vj0*8 + (lane>>3))*MSEQ
                                   + (((lane&7) ^ ((lane>>3)&7)) * 8);
    const unsigned short* Vg1 = Vg0 + (size_t)8*MSEQ;
    const int* Mg = mask + b*MSEQ + lane*4;   // lanes<16 only

#define ATT_STAGE(bufi, kn)                                                   \
  {                                                                           \
    gl_lds16(Vg0 + (kn), &Vs[bufi][vj0*512]);                                 \
    gl_lds16(Vg1 + (kn), &Vs[bufi][(vj0+1)*512]);                             \
    if (w == 0) {                                                             \
      gl_lds16(Kg + (size_t)(kn)*128,      &Ks[bufi][0]);                     \
      gl_lds16(Kg + (size_t)((kn)+32)*128, &Ks[bufi][32*16]);                 \
    }                                                                         \
    if (w == 1 && lane < 16) gl_lds16(Mg + (kn), &Ms[bufi][0]);               \
  }

    f32x4 O[4];
    #pragma unroll
    for (int v = 0; v < 4; ++v) O[v] = {0.f,0.f,0.f,0.f};
    float ws = 0.f;

    ATT_STAGE(0, 0)
    asm volatile("s_waitcnt vmcnt(0)" ::: "memory");
    __syncthreads();

    for (int kt = 0; kt < 32; ++kt) {
        const int cur = kt & 1;
        if (kt < 31) ATT_STAGE(cur ^ 1, (kt+1)*64)

        const short* Kc = Ks[cur];
        const short* Vc = Vs[cur];
        const int*   Mc = Ms[cur];

        #pragma unroll
        for (int s = 0; s < 4; ++s) {
            const int krow = s*16 + l15;
            const int kg = ((quad>>1) ^ ((krow>>2)&1));     // swizzled K granule
            const short4v kf = *(const short4v*)&Kc[krow*16 + kg*8 + (quad&1)*4];
            const int4 mk = *(const int4*)&Mc[s*16 + quad*4];
            f32x4 sc = {0.f,0.f,0.f,0.f};
            sc = mfma16(kf, qf, sc);
            // lane: q=l15, keys = s*16 + quad*4 + r; K pre-scaled by 0.25*log2e
            const float w0 = mk.x ? fast_exp2(fmaxf(sc[0], 0.f)) : 0.f;
            const float w1 = mk.y ? fast_exp2(fmaxf(sc[1], 0.f)) : 0.f;
            const float w2 = mk.z ? fast_exp2(fmaxf(sc[2], 0.f)) : 0.f;
            const float w3 = mk.w ? fast_exp2(fmaxf(sc[3], 0.f)) : 0.f;
            ws += (w0 + w1) + (w2 + w3);
            short4v pf;
            pf[0]=bf16b(w0); pf[1]=bf16b(w1); pf[2]=bf16b(w2); pf[3]=bf16b(w3);
            #pragma unroll
            for (int v = 0; v < 4; ++v) {
                const int ch = v*16 + l15;
                const int g = (2*s + (quad>>1)) ^ (ch & 7);    // swizzled V granule
                const short4v vf = *(const short4v*)&Vc[ch*64 + g*8 + (quad&1)*4];
                O[v] = mfma16(pf, vf, O[v]);
            }
        }
        asm volatile("s_waitcnt vmcnt(0)" ::: "memory");
        __syncthreads();
    }

    // wsum for q=l15: fold the 4 quads (every lane ends with full sum)
    ws += __shfl_xor(ws, 16, 64);
    ws += __shfl_xor(ws, 32, 64);
    const float g = gamma[0];
    // O lane layout: O[v][r] = O[q=quad*4+r][ch=v*16+l15]
    float inv[4];
    #pragma unroll
    for (int r = 0; r < 4; ++r)
        inv[r] = g / fmaxf(__shfl(ws, quad*4 + r, 64), 1e-20f);

    float* op = out + (size_t)(b*MSEQ + mq + quad*4)*512 + h*64 + l15;
    #pragma unroll
    for (int r = 0; r < 4; ++r) {
        op[(size_t)r*512 +  0] = O[0][r] * inv[r];
        op[(size_t)r*512 + 16] = O[1][r] * inv[r];
        op[(size_t)r*512 + 32] = O[2][r] * inv[r];
        op[(size_t)r*512 + 48] = O[3][r] * inv[r];
    }
#undef ATT_STAGE
}

extern "C" void kernel_launch(void* const* d_in, const int* in_sizes, int n_in,
                              void* d_out, int out_size, void* d_ws, size_t ws_size,
                              hipStream_t stream) {
    const float* x     = (const float*)d_in[0];
    const int*   mask  = (const int*)  d_in[1];
    const float* Wq    = (const float*)d_in[2];
    const float* bq    = (const float*)d_in[3];
    const float* Wk    = (const float*)d_in[4];
    const float* bk    = (const float*)d_in[5];
    const float* Wv    = (const float*)d_in[6];
    const float* bv    = (const float*)d_in[7];
    const float* gamma = (const float*)d_in[8];
    float* outp = (float*)d_out;

    // ws (bf16 shorts): xb 8MB | WT 0.75MB | Qb 2MB | Kb 2MB | Vt 8MB
    unsigned short* xb = (unsigned short*)d_ws;
    unsigned short* WT = xb + (size_t)8192*512;
    unsigned short* Qb = WT + (size_t)768*512;
    unsigned short* Kb = Qb + (size_t)8192*128;
    unsigned short* Vt = Kb + (size_t)8192*128;

    xcvt_kernel<<<2048, 256, 0, stream>>>(x, xb);
    wtrans_kernel<<<dim3(12, 8), 256, 0, stream>>>(Wq, Wk, Wv, WT);
    proj_mfma<<<dim3(6, 128), 256, 0, stream>>>(xb, WT, bq, bk, bv, Qb, Kb, Vt);
    attn_mfma<<<dim3(32, 32), 256, 0, stream>>>(Qb, Kb, Vt, mask, gamma, outp);
}

// Round 7
// 152.827 us; speedup vs baseline: 2.6038x; 1.0234x over previous
//
#include <hip/hip_runtime.h>
#include <hip/hip_bf16.h>

#define MSEQ 2048

typedef __attribute__((ext_vector_type(8))) short short8;
typedef __attribute__((ext_vector_type(4))) short short4v;
typedef __attribute__((ext_vector_type(4))) float f32x4;

static __device__ __forceinline__ short bf16b(float f) {
    __hip_bfloat16 h = __float2bfloat16(f);   // RNE
    return *reinterpret_cast<short*>(&h);
}

// raw 2^x (input is pre-scaled by log2e at the K projection)
static __device__ __forceinline__ float fast_exp2(float x) {
    float r;
    asm("v_exp_f32 %0, %1" : "=v"(r) : "v"(x));
    return r;
}

// 16x16x16 bf16 MFMA (DQK=16 exact; score D-layout == PV A-frag layout)
static __device__ __forceinline__ f32x4 mfma16(short4v a, short4v b, f32x4 c) {
    return __builtin_amdgcn_mfma_f32_16x16x16bf16_1k(a, b, c, 0, 0, 0);
}

// async global->LDS, 16B per lane; LDS dest = wave-uniform base + lane*16
static __device__ __forceinline__ void gl_lds16(const void* g, void* l) {
    __builtin_amdgcn_global_load_lds(
        (const __attribute__((address_space(1))) unsigned int*)g,
        (__attribute__((address_space(3))) unsigned int*)l, 16, 0, 0);
}

// ---------------- prep: x fp32->bf16 | W->WT[n][k] bf16 | mask->bf16 ----------------
// blocks 0..2047: xcvt; 2048..2143: wtrans; 2144: mask cvt.
__global__ __launch_bounds__(256) void prep_kernel(
    const float* __restrict__ x, unsigned short* __restrict__ xb,
    const float* __restrict__ Wq, const float* __restrict__ Wk,
    const float* __restrict__ Wv, unsigned short* __restrict__ WT,
    const int* __restrict__ mask, unsigned short* __restrict__ maskbf)
{
    __shared__ unsigned short Ts[64*72];   // wtrans only
    const int bid = blockIdx.x;
    const int t = threadIdx.x;

    if (bid < 2048) {                      // ---- x cvt ----
        const size_t i = ((size_t)bid * 256 + t) * 8;
        const float4 a = *(const float4*)(x + i);
        const float4 b = *(const float4*)(x + i + 4);
        short8 o;
        o[0]=bf16b(a.x); o[1]=bf16b(a.y); o[2]=bf16b(a.z); o[3]=bf16b(a.w);
        o[4]=bf16b(b.x); o[5]=bf16b(b.y); o[6]=bf16b(b.z); o[7]=bf16b(b.w);
        *(short8*)(xb + i) = o;
        return;
    }
    if (bid == 2144) {                     // ---- mask -> bf16 (0/1 exact) ----
        #pragma unroll
        for (int j = 0; j < 8; ++j) {
            const int4 m4 = *(const int4*)(mask + (t*8 + j)*4);
            short4v o;
            o[0]=bf16b((float)m4.x); o[1]=bf16b((float)m4.y);
            o[2]=bf16b((float)m4.z); o[3]=bf16b((float)m4.w);
            *(short4v*)(maskbf + (t*8 + j)*4) = o;
        }
        return;
    }
    // ---- wtrans ----
    const int idx = bid - 2048;            // 96 blocks
    const int nt = idx >> 3;               // 12 tiles of 64 n
    const int kt = idx & 7;                // 8 tiles of 64 k
    const int k0 = kt*64;

    const float* W; int ld, n0;
    if (nt < 2)      { W = Wq; ld = 128; n0 = nt*64; }
    else if (nt < 4) { W = Wk; ld = 128; n0 = (nt-2)*64; }
    else             { W = Wv; ld = 512; n0 = (nt-4)*64; }

    #pragma unroll
    for (int s = 0; s < 4; ++s) {
        const int lin = s*256 + t;
        const int krow = lin >> 4, ng = lin & 15;
        const float4 v = *(const float4*)(W + (size_t)(k0+krow)*ld + n0 + ng*4);
        Ts[(ng*4+0)*72 + krow] = (unsigned short)bf16b(v.x);
        Ts[(ng*4+1)*72 + krow] = (unsigned short)bf16b(v.y);
        Ts[(ng*4+2)*72 + krow] = (unsigned short)bf16b(v.z);
        Ts[(ng*4+3)*72 + krow] = (unsigned short)bf16b(v.w);
    }
    __syncthreads();
    #pragma unroll
    for (int s = 0; s < 2; ++s) {
        const int lin = s*256 + t;
        const int nrow = lin >> 3, kg = lin & 7;
        *(short8*)(WT + (size_t)(nt*64 + nrow)*512 + k0 + kg*8) = *(const short8*)&Ts[nrow*72 + kg*8];
    }
}

// ---------------- Fused projection GEMM, bf16 MFMA, 64x128 tiles ----------------
// SAFE double-buffer (T3 pattern): STAGE(cur^1) issued before COMPUTE(cur); the
// end-of-iteration __syncthreads (full vmcnt/lgkmcnt drain) separates all waves'
// reads of a buffer from the next overwrite. DMA latency hides under compute.
// nt==1 (K) pre-scaled by 0.25*log2(e). nt>=2 (V) pre-masked: Vt *= mask[key].
__global__ __launch_bounds__(256, 3) void proj_mfma(
    const unsigned short* __restrict__ xb, const unsigned short* __restrict__ WT,
    const float* __restrict__ bq, const float* __restrict__ bk, const float* __restrict__ bv,
    const int* __restrict__ mask,
    unsigned short* __restrict__ Qb, unsigned short* __restrict__ Kb, unsigned short* __restrict__ Vt)
{
    const int nt = blockIdx.x;        // 0..5 (0=Q,1=K,2..5=V)
    const int r0 = blockIdx.y * 64;   // m (128 tiles)
    const int n0 = nt * 128;
    const int t = threadIdx.x, w = t >> 6, lane = t & 63, l15 = lane & 15, quad = lane >> 4;
    const int qh = w >> 1, chh = w & 1;

    __shared__ short smem[12288];     // As[2][2048] | Bs[2][4096]; Ts aliases (<=9216)
    short* As = smem;                 // buf stride 2048 shorts (4096B)
    short* Bs = smem + 4096;          // buf stride 4096 shorts (8192B)

    f32x4 acc[2][4];
    #pragma unroll
    for (int i = 0; i < 2; ++i)
        #pragma unroll
        for (int j = 0; j < 4; ++j) acc[i][j] = {0.f,0.f,0.f,0.f};

    const int arow = lane >> 2, akg = lane & 3;

#define PROJ_STAGE(BUFI, KK) {                                                          \
    gl_lds16(xb + (size_t)(r0 + w*16 + arow)*512 + (KK) + akg*8,                        \
             (char*)As + (BUFI)*4096 + w*1024);                                         \
    gl_lds16(WT + (size_t)(n0 + w*16 + arow)*512 + (KK) + akg*8,                        \
             (char*)Bs + (BUFI)*8192 + w*1024);                                         \
    gl_lds16(WT + (size_t)(n0 + 64 + w*16 + arow)*512 + (KK) + akg*8,                   \
             (char*)Bs + (BUFI)*8192 + 4096 + w*1024);                                  \
}

    PROJ_STAGE(0, 0)
    __syncthreads();

    #pragma unroll 1
    for (int kp = 0; kp < 16; ++kp) {
        const int cur = kp & 1;
        if (kp < 15) PROJ_STAGE(cur ^ 1, (kp+1)*32)
        short8 Af[2], Bf[4];
        #pragma unroll
        for (int i = 0; i < 2; ++i)
            Af[i] = *(const short8*)&As[cur*2048 + (qh*32 + i*16 + l15)*32 + quad*8];
        #pragma unroll
        for (int j = 0; j < 4; ++j)
            Bf[j] = *(const short8*)&Bs[cur*4096 + (chh*64 + j*16 + l15)*32 + quad*8];
        #pragma unroll
        for (int i = 0; i < 2; ++i)
            #pragma unroll
            for (int j = 0; j < 4; ++j)
                acc[i][j] = __builtin_amdgcn_mfma_f32_16x16x32_bf16(Af[i], Bf[j], acc[i][j], 0, 0, 0);
        __syncthreads();   // reads of cur done (lgkm drained); next iter may overwrite
    }

    const float* bias = (nt == 0) ? bq : (nt == 1) ? bk : (bv + (nt-2)*128);
    const float kscale = (nt == 1) ? 0.36067376022224085f : 1.0f;  // 0.25 * log2(e)
    float bj[4];
    #pragma unroll
    for (int j = 0; j < 4; ++j) bj[j] = bias[chh*64 + j*16 + l15];

    const int bb = r0 >> 11, key0 = r0 & 2047;
    short* Ts = smem;
    if (nt < 2) {       // row-major [64 m][136]
        #pragma unroll
        for (int i = 0; i < 2; ++i)
            #pragma unroll
            for (int j = 0; j < 4; ++j)
                #pragma unroll
                for (int r = 0; r < 4; ++r)
                    Ts[(qh*32 + i*16 + quad*4 + r)*136 + chh*64 + j*16 + l15] =
                        bf16b((acc[i][j][r] + bj[j]) * kscale);
    } else {            // transposed [128 ch][72 key], pre-masked by key
        float mv[2][4];
        #pragma unroll
        for (int i = 0; i < 2; ++i)
            #pragma unroll
            for (int r = 0; r < 4; ++r)
                mv[i][r] = (float)mask[bb*MSEQ + key0 + qh*32 + i*16 + quad*4 + r];
        #pragma unroll
        for (int i = 0; i < 2; ++i)
            #pragma unroll
            for (int j = 0; j < 4; ++j)
                #pragma unroll
                for (int r = 0; r < 4; ++r)
                    Ts[(chh*64 + j*16 + l15)*72 + qh*32 + i*16 + quad*4 + r] =
                        bf16b((acc[i][j][r] + bj[j]) * mv[i][r]);
    }
    __syncthreads();

    if (nt < 2) {
        unsigned short* Out = (nt == 0) ? Qb : Kb;
        #pragma unroll
        for (int s = 0; s < 4; ++s) {
            const int lin = s*256 + t, row = lin >> 4, seg = lin & 15;
            *(short8*)(Out + (size_t)(r0+row)*128 + seg*8) = *(const short8*)&Ts[row*136 + seg*8];
        }
    } else {
        const int chBase = (nt-2)*128;
        #pragma unroll
        for (int s = 0; s < 4; ++s) {
            const int lin = s*256 + t, row = lin >> 3, seg = lin & 7;
            *(short8*)(Vt + ((size_t)(bb*512 + chBase + row))*MSEQ + key0 + seg*8) =
                *(const short8*)&Ts[row*72 + seg*8];
        }
    }
#undef PROJ_STAGE
}

// ---------------- Fused masked attention ----------------
// Round-5's proven race-free loop: STAGE(cur^1) -> COMPUTE(cur) -> __syncthreads
// (stage never targets the buffer being read; the full-drain barrier separates
// reads from the next overwrite). Round-6 algebraic cuts kept: mask folded into
// V at projection + bf16 mask frag; wsum via one extra mfma16 whose D-layout
// lands WS[r] on exactly the lane applying inv[r] (no cndmask/adds/shuffles);
// LDS read offsets hoisted (1 XOR per V read).
__global__ __launch_bounds__(256, 4) void attn_mfma(
    const unsigned short* __restrict__ Qb, const unsigned short* __restrict__ Kb,
    const unsigned short* __restrict__ Vt, const unsigned short* __restrict__ maskbf,
    const float* __restrict__ gamma, float* __restrict__ out)
{
    // XCD-aware bijective remap: each XCD owns 4 consecutive bh slices (L2-resident)
    const int bid = blockIdx.y * 32 + blockIdx.x;      // 1024 blocks, 1024%8==0
    const int lin = (bid & 7) * 128 + (bid >> 3);
    const int mt = lin & 31, bh = lin >> 5;
    const int b  = bh >> 3, h = bh & 7;
    const int m0 = mt * 64;
    const int t  = threadIdx.x;
    const int w = t >> 6, lane = t & 63, l15 = lane & 15, quad = lane >> 4;
    const int mq = m0 + w*16;            // this wave's 16 q rows

    __shared__ __align__(16) short Ks[2][64*16];   // [key][16 d], granule-swizzled
    __shared__ __align__(16) short Vs[2][64*64];   // [ch][64 key], granule-swizzled, pre-masked
    __shared__ __align__(16) short Msb[2][64];     // bf16 mask per key

    // Q B-frag: n=q=l15, k=d=quad*4+j
    const short4v qf = *(const short4v*)(Qb + (size_t)(b*MSEQ + mq + l15)*128 + h*16 + quad*4);

    // staging sources (per-lane, swizzle pre-applied on the global side)
    const unsigned short* Kg = Kb + (size_t)(b*MSEQ + (lane>>1))*128 + h*16
                              + (((lane&1) ^ ((lane>>3)&1))*8);
    const int vj0 = 2*w;
    const unsigned short* Vg0 = Vt + (size_t)(b*512 + h*64 + vj0*8 + (lane>>3))*MSEQ
                               + (((lane&7) ^ ((lane>>3)&7)) * 8);
    const unsigned short* Vg1 = Vg0 + (size_t)8*MSEQ;
    const unsigned short* Mgb = maskbf + b*MSEQ + lane*8;   // lanes<8 only

#define ATT_STAGE(BUFI, KN) {                                                       \
    gl_lds16(Vg0 + (KN), &Vs[BUFI][vj0*512]);                                       \
    gl_lds16(Vg1 + (KN), &Vs[BUFI][(vj0+1)*512]);                                   \
    if (w < 2)          gl_lds16(Kg + (size_t)((KN) + w*32)*128, &Ks[BUFI][w*32*16]);\
    else if (lane < 8)  gl_lds16(Mgb + (KN), &Msb[BUFI][0]);                        \
}

    // hoisted LDS read offsets (bytes)
    const char* KsB = (const char*)&Ks[0][0];
    const char* VsB = (const char*)&Vs[0][0];
    const char* MsB = (const char*)&Msb[0][0];
    const int kofs = l15*32 + (((quad>>1) ^ ((l15>>2)&1))*16) + (quad&1)*8;
    const int mofs = quad*8;
    int vb[4];
    #pragma unroll
    for (int v = 0; v < 4; ++v) {
        const int ch = v*16 + l15;
        vb[v] = ch*128 + (((quad>>1) ^ (ch&7))*16) + (quad&1)*8;
    }

    f32x4 O[4];
    #pragma unroll
    for (int v = 0; v < 4; ++v) O[v] = {0.f,0.f,0.f,0.f};
    f32x4 WS = {0.f,0.f,0.f,0.f};

    ATT_STAGE(0, 0)
    __syncthreads();

    #pragma unroll 1
    for (int kt = 0; kt < 32; ++kt) {
        const int cur = kt & 1;
        if (kt < 31) ATT_STAGE(cur ^ 1, (kt+1)*64)

        const char* Kc = KsB + cur*2048;
        const char* Vc = VsB + cur*8192;
        const char* Mc = MsB + cur*128;

        #pragma unroll
        for (int s = 0; s < 4; ++s) {
            const short4v kf  = *(const short4v*)(Kc + kofs + s*512);
            const short4v mkf = *(const short4v*)(Mc + mofs + s*32);
            f32x4 sc = {0.f,0.f,0.f,0.f};
            sc = mfma16(kf, qf, sc);
            // lane: q=l15, keys = s*16+quad*4+r; K pre-scaled by 0.25*log2e
            const float w0 = fast_exp2(fmaxf(sc[0], 0.f));
            const float w1 = fast_exp2(fmaxf(sc[1], 0.f));
            const float w2 = fast_exp2(fmaxf(sc[2], 0.f));
            const float w3 = fast_exp2(fmaxf(sc[3], 0.f));
            short4v pf;
            pf[0]=bf16b(w0); pf[1]=bf16b(w1); pf[2]=bf16b(w2); pf[3]=bf16b(w3);
            WS = mfma16(pf, mkf, WS);          // wsum: D row q = quad*4+r on this lane
            #pragma unroll
            for (int v = 0; v < 4; ++v) {
                const short4v vf = *(const short4v*)(Vc + (vb[v] ^ (s*32)));
                O[v] = mfma16(pf, vf, O[v]);   // V pre-masked -> masked keys add 0
            }
        }
        __syncthreads();   // full drain: reads of cur done; stage of cur^1 landed
    }

    // WS[r] = masked wsum for q = quad*4+r — same lane that owns O[.][r].
    const float g = gamma[0];
    float inv[4];
    #pragma unroll
    for (int r = 0; r < 4; ++r) inv[r] = g / fmaxf(WS[r], 1e-20f);

    float* op = out + (size_t)(b*MSEQ + mq + quad*4)*512 + h*64 + l15;
    #pragma unroll
    for (int r = 0; r < 4; ++r) {
        op[(size_t)r*512 +  0] = O[0][r] * inv[r];
        op[(size_t)r*512 + 16] = O[1][r] * inv[r];
        op[(size_t)r*512 + 32] = O[2][r] * inv[r];
        op[(size_t)r*512 + 48] = O[3][r] * inv[r];
    }
#undef ATT_STAGE
}

extern "C" void kernel_launch(void* const* d_in, const int* in_sizes, int n_in,
                              void* d_out, int out_size, void* d_ws, size_t ws_size,
                              hipStream_t stream) {
    const float* x     = (const float*)d_in[0];
    const int*   mask  = (const int*)  d_in[1];
    const float* Wq    = (const float*)d_in[2];
    const float* bq    = (const float*)d_in[3];
    const float* Wk    = (const float*)d_in[4];
    const float* bk    = (const float*)d_in[5];
    const float* Wv    = (const float*)d_in[6];
    const float* bv    = (const float*)d_in[7];
    const float* gamma = (const float*)d_in[8];
    float* outp = (float*)d_out;

    // ws (bf16 shorts): xb 8MB | WT 0.75MB | Qb 2MB | Kb 2MB | Vt 8MB | maskbf 16KB
    unsigned short* xb = (unsigned short*)d_ws;
    unsigned short* WT = xb + (size_t)8192*512;
    unsigned short* Qb = WT + (size_t)768*512;
    unsigned short* Kb = Qb + (size_t)8192*128;
    unsigned short* Vt = Kb + (size_t)8192*128;
    unsigned short* maskbf = Vt + (size_t)2048*MSEQ;

    prep_kernel<<<2145, 256, 0, stream>>>(x, xb, Wq, Wk, Wv, WT, mask, maskbf);
    proj_mfma<<<dim3(6, 128), 256, 0, stream>>>(xb, WT, bq, bk, bv, mask, Qb, Kb, Vt);
    attn_mfma<<<dim3(32, 32), 256, 0, stream>>>(Qb, Kb, Vt, maskbf, gamma, outp);
}